// Round 4
// baseline (274.268 us; speedup 1.0000x reference)
//
#include <hip/hip_runtime.h>

#define B_ROWS 4096
#define N_COLS 8192
#define BLOCK  256
#define VPT    (N_COLS / 4 / BLOCK)   // float4 loads per thread per input = 8

// One block per row: 5 fused reductions + per-row loss.
//
// R1-R3 lesson: the AMDGPU machine scheduler sinks loads next to their uses
// (VGPR=32..36) no matter how the source batches them, leaving ~2 loads in
// flight per wave -> latency-bound at 2.7 TB/s effective. sched_barrier(0)
// forbids any instruction from crossing, forcing all 16 global_load_dwordx4
// to issue before the first consume (64 data VGPRs live, 16 KB/wave in
// flight). launch_bounds(256,2) permits the register budget.
__global__ __launch_bounds__(BLOCK, 2) void row_pearson_kernel(
    const float* __restrict__ preds,
    const float* __restrict__ labels,
    float* __restrict__ row_loss)
{
    const int row = blockIdx.x;
    const int tid = threadIdx.x;

    const float4* p4 = reinterpret_cast<const float4*>(preds  + (size_t)row * N_COLS);
    const float4* l4 = reinterpret_cast<const float4*>(labels + (size_t)row * N_COLS);

    // Issue ALL 16 loads; nothing may be scheduled across the barrier below,
    // so these cannot be sunk into the compute loop.
    float4 x[VPT], y[VPT];
    #pragma unroll
    for (int i = 0; i < VPT; ++i) {
        x[i] = p4[tid + i * BLOCK];
        y[i] = l4[tid + i * BLOCK];
    }
    __builtin_amdgcn_sched_barrier(0);

    // Two independent accumulator sets to shorten the FMA dep chain.
    float sx0 = 0.f, sy0 = 0.f, sxy0 = 0.f, sxx0 = 0.f, syy0 = 0.f;
    float sx1 = 0.f, sy1 = 0.f, sxy1 = 0.f, sxx1 = 0.f, syy1 = 0.f;
    #pragma unroll
    for (int i = 0; i < VPT; i += 2) {
        {
            const float4 a = x[i], b = y[i];
            sx0  += a.x + a.y + a.z + a.w;
            sy0  += b.x + b.y + b.z + b.w;
            sxy0 += a.x * b.x + a.y * b.y + a.z * b.z + a.w * b.w;
            sxx0 += a.x * a.x + a.y * a.y + a.z * a.z + a.w * a.w;
            syy0 += b.x * b.x + b.y * b.y + b.z * b.z + b.w * b.w;
        }
        {
            const float4 a = x[i + 1], b = y[i + 1];
            sx1  += a.x + a.y + a.z + a.w;
            sy1  += b.x + b.y + b.z + b.w;
            sxy1 += a.x * b.x + a.y * b.y + a.z * b.z + a.w * b.w;
            sxx1 += a.x * a.x + a.y * a.y + a.z * a.z + a.w * a.w;
            syy1 += b.x * b.x + b.y * b.y + b.z * b.z + b.w * b.w;
        }
    }
    float sx = sx0 + sx1, sy = sy0 + sy1, sxy = sxy0 + sxy1;
    float sxx = sxx0 + sxx1, syy = syy0 + syy1;

    // 64-lane wave reduction (wave = 64 on gfx950).
    #pragma unroll
    for (int off = 32; off > 0; off >>= 1) {
        sx  += __shfl_down(sx,  off);
        sy  += __shfl_down(sy,  off);
        sxy += __shfl_down(sxy, off);
        sxx += __shfl_down(sxx, off);
        syy += __shfl_down(syy, off);
    }

    __shared__ float smem[4][5];   // 4 waves per block
    const int wave = tid >> 6;
    const int lane = tid & 63;
    if (lane == 0) {
        smem[wave][0] = sx;  smem[wave][1] = sy;  smem[wave][2] = sxy;
        smem[wave][3] = sxx; smem[wave][4] = syy;
    }
    __syncthreads();

    if (tid == 0) {
        float tx = 0.f, ty = 0.f, txy = 0.f, txx = 0.f, tyy = 0.f;
        #pragma unroll
        for (int w = 0; w < BLOCK / 64; ++w) {
            tx  += smem[w][0]; ty  += smem[w][1]; txy += smem[w][2];
            txx += smem[w][3]; tyy += smem[w][4];
        }
        const float Nf  = (float)N_COLS;
        const float num = Nf * txy - tx * ty;
        const float den = sqrtf((Nf * txx - tx * tx) * (Nf * tyy - ty * ty));
        row_loss[row] = 1.0f - num / den;
    }
}

// Reduce 4096 per-row losses to the mean. Single block.
__global__ __launch_bounds__(BLOCK) void mean_kernel(
    const float* __restrict__ row_loss,
    float* __restrict__ out)
{
    const int tid = threadIdx.x;

    float v[B_ROWS / BLOCK];
    #pragma unroll
    for (int i = 0; i < B_ROWS / BLOCK; ++i)
        v[i] = row_loss[tid + i * BLOCK];

    float s = 0.f;
    #pragma unroll
    for (int i = 0; i < B_ROWS / BLOCK; ++i)
        s += v[i];

    #pragma unroll
    for (int off = 32; off > 0; off >>= 1)
        s += __shfl_down(s, off);

    __shared__ float smem[4];
    const int wave = tid >> 6;
    const int lane = tid & 63;
    if (lane == 0) smem[wave] = s;
    __syncthreads();

    if (tid == 0) {
        float t = smem[0] + smem[1] + smem[2] + smem[3];
        out[0] = t / (float)B_ROWS;
    }
}

extern "C" void kernel_launch(void* const* d_in, const int* in_sizes, int n_in,
                              void* d_out, int out_size, void* d_ws, size_t ws_size,
                              hipStream_t stream) {
    const float* preds  = (const float*)d_in[0];
    const float* labels = (const float*)d_in[1];
    float* row_loss = (float*)d_ws;      // 4096 floats of scratch
    float* out      = (float*)d_out;

    row_pearson_kernel<<<B_ROWS, BLOCK, 0, stream>>>(preds, labels, row_loss);
    mean_kernel<<<1, BLOCK, 0, stream>>>(row_loss, out);
}

// Round 5
// 272.656 us; speedup vs baseline: 1.0059x; 1.0059x over previous
//
#include <hip/hip_runtime.h>

#define B_ROWS 4096
#define N_COLS 8192
#define BLOCK  256
#define F4_PER_ROW (N_COLS / 4)   // 2048 float4 per row
#define ISSUES 8                  // DMA issues per wave per input (512 f4 / 64 lanes)

// R1-R4 lessons:
//  - compiler pins register-based loads to ~2 in flight/wave regardless of
//    source structure, launch_bounds, or sched_barrier (VGPR 32..44).
//  - occupancy/MLP tweaks are throughput-neutral: kernel is pinned at
//    ~2.7 TB/s effective while WRITE_SIZE shows ~130 MB of concurrent
//    harness restore traffic -> we're getting a fair share of a saturated
//    fabric.
//  - global_load_lds gives vmcnt-tracked DMA with NO result registers:
//    16 x dwordx4 issued back-to-back per wave (16 KB in flight), one drain.
//
// Layout: wave w stages and reads its own quarter-row (self-aligned, so no
// cross-wave LDS-DMA visibility assumptions). LDS dst = wave-uniform base +
// lane*16 (m104/m108 semantics) matches the contiguous layout exactly.

typedef const __attribute__((address_space(1))) void* gas_ptr;
typedef __attribute__((address_space(3))) void* las_ptr;

__global__ __launch_bounds__(BLOCK) void row_pearson_kernel(
    const float* __restrict__ preds,
    const float* __restrict__ labels,
    float* __restrict__ row_loss)
{
    __shared__ float4 sX[F4_PER_ROW];   // 32 KB
    __shared__ float4 sY[F4_PER_ROW];   // 32 KB
    __shared__ float partials[4][5];

    const int row  = blockIdx.x;
    const int tid  = threadIdx.x;
    const int w    = tid >> 6;
    const int lane = tid & 63;

    const float4* p4 = reinterpret_cast<const float4*>(preds  + (size_t)row * N_COLS);
    const float4* l4 = reinterpret_cast<const float4*>(labels + (size_t)row * N_COLS);

    // Stage: 16 async DMA issues per wave, no result VGPRs consumed.
    // Wave w covers float4 indices [w*512, (w+1)*512).
    #pragma unroll
    for (int i = 0; i < ISSUES; ++i) {
        const int g = (w << 9) + (i << 6) + lane;
        __builtin_amdgcn_global_load_lds((gas_ptr)(p4 + g), (las_ptr)(sX + g), 16, 0, 0);
        __builtin_amdgcn_global_load_lds((gas_ptr)(l4 + g), (las_ptr)(sY + g), 16, 0, 0);
    }
    __syncthreads();   // single vmcnt drain + barrier; DMA batch stays 16-deep

    // Read back own quarter-row from LDS (ds_read_b128, contiguous -> no
    // bank conflicts) and accumulate the 5 sums.
    float sx = 0.f, sy = 0.f, sxy = 0.f, sxx = 0.f, syy = 0.f;
    #pragma unroll
    for (int i = 0; i < ISSUES; ++i) {
        const int g = (w << 9) + (i << 6) + lane;
        const float4 a = sX[g];
        const float4 b = sY[g];
        sx  += a.x + a.y + a.z + a.w;
        sy  += b.x + b.y + b.z + b.w;
        sxy += a.x * b.x + a.y * b.y + a.z * b.z + a.w * b.w;
        sxx += a.x * a.x + a.y * a.y + a.z * a.z + a.w * a.w;
        syy += b.x * b.x + b.y * b.y + b.z * b.z + b.w * b.w;
    }

    // 64-lane wave reduction.
    #pragma unroll
    for (int off = 32; off > 0; off >>= 1) {
        sx  += __shfl_down(sx,  off);
        sy  += __shfl_down(sy,  off);
        sxy += __shfl_down(sxy, off);
        sxx += __shfl_down(sxx, off);
        syy += __shfl_down(syy, off);
    }

    if (lane == 0) {
        partials[w][0] = sx;  partials[w][1] = sy;  partials[w][2] = sxy;
        partials[w][3] = sxx; partials[w][4] = syy;
    }
    __syncthreads();

    if (tid == 0) {
        float tx = 0.f, ty = 0.f, txy = 0.f, txx = 0.f, tyy = 0.f;
        #pragma unroll
        for (int v = 0; v < 4; ++v) {
            tx  += partials[v][0]; ty  += partials[v][1]; txy += partials[v][2];
            txx += partials[v][3]; tyy += partials[v][4];
        }
        const float Nf  = (float)N_COLS;
        const float num = Nf * txy - tx * ty;
        const float den = sqrtf((Nf * txx - tx * tx) * (Nf * tyy - ty * ty));
        row_loss[row] = 1.0f - num / den;
    }
}

// Reduce 4096 per-row losses to the mean. Single block.
__global__ __launch_bounds__(BLOCK) void mean_kernel(
    const float* __restrict__ row_loss,
    float* __restrict__ out)
{
    const int tid = threadIdx.x;

    float s = 0.f;
    #pragma unroll
    for (int i = 0; i < B_ROWS / BLOCK; ++i)
        s += row_loss[tid + i * BLOCK];

    #pragma unroll
    for (int off = 32; off > 0; off >>= 1)
        s += __shfl_down(s, off);

    __shared__ float smem[4];
    const int wave = tid >> 6;
    const int lane = tid & 63;
    if (lane == 0) smem[wave] = s;
    __syncthreads();

    if (tid == 0) {
        float t = smem[0] + smem[1] + smem[2] + smem[3];
        out[0] = t / (float)B_ROWS;
    }
}

extern "C" void kernel_launch(void* const* d_in, const int* in_sizes, int n_in,
                              void* d_out, int out_size, void* d_ws, size_t ws_size,
                              hipStream_t stream) {
    const float* preds  = (const float*)d_in[0];
    const float* labels = (const float*)d_in[1];
    float* row_loss = (float*)d_ws;      // 4096 floats of scratch
    float* out      = (float*)d_out;

    row_pearson_kernel<<<B_ROWS, BLOCK, 0, stream>>>(preds, labels, row_loss);
    mean_kernel<<<1, BLOCK, 0, stream>>>(row_loss, out);
}

// Round 7
// 246.304 us; speedup vs baseline: 1.1135x; 1.1070x over previous
//
#include <hip/hip_runtime.h>

#define B_ROWS 4096
#define N_COLS 8192
#define BLOCK  256
#define VPT    (N_COLS / 4 / BLOCK)   // float4 loads per thread per input = 8

// Native clang vector type: __builtin_nontemporal_load requires a pointer to
// scalar/vector-of-scalar, not HIP's HIP_vector_type struct.
typedef float vfloat4 __attribute__((ext_vector_type(4)));

// R1-R5 post-mortems: kernel is pinned at ~2.7 TB/s effective (10.5 GB/s/CU)
// regardless of per-wave queue depth (2..16 loads), occupancy (14..67%), or
// memory path (VGPR loads vs global_load_lds DMA). FETCH_SIZE == exactly one
// input buffer: preds streams from HBM (1.35 TB/s), labels is fully
// L3-resident (1.35 TB/s of hits). Hypothesis: the wall is Infinity-Cache
// internal traffic — every preds miss probes AND fills L3 (evicting labels),
// so L3 does ~2.7 TB/s internally. Non-temporal loads skip allocation on
// miss: L3 serves hits only, preds streams from HBM unthrottled.
__global__ __launch_bounds__(BLOCK) void row_pearson_kernel(
    const float* __restrict__ preds,
    const float* __restrict__ labels,
    float* __restrict__ row_loss)
{
    const int row = blockIdx.x;
    const int tid = threadIdx.x;

    const vfloat4* p4 = reinterpret_cast<const vfloat4*>(preds  + (size_t)row * N_COLS);
    const vfloat4* l4 = reinterpret_cast<const vfloat4*>(labels + (size_t)row * N_COLS);

    float sx = 0.f, sy = 0.f, sxy = 0.f, sxx = 0.f, syy = 0.f;

    #pragma unroll
    for (int i = 0; i < VPT; ++i) {
        const vfloat4 x = __builtin_nontemporal_load(p4 + tid + i * BLOCK);
        const vfloat4 y = __builtin_nontemporal_load(l4 + tid + i * BLOCK);
        sx  += x.x + x.y + x.z + x.w;
        sy  += y.x + y.y + y.z + y.w;
        sxy += x.x * y.x + x.y * y.y + x.z * y.z + x.w * y.w;
        sxx += x.x * x.x + x.y * x.y + x.z * x.z + x.w * x.w;
        syy += y.x * y.x + y.y * y.y + y.z * y.z + y.w * y.w;
    }

    // 64-lane wave reduction (wave = 64 on gfx950).
    #pragma unroll
    for (int off = 32; off > 0; off >>= 1) {
        sx  += __shfl_down(sx,  off);
        sy  += __shfl_down(sy,  off);
        sxy += __shfl_down(sxy, off);
        sxx += __shfl_down(sxx, off);
        syy += __shfl_down(syy, off);
    }

    __shared__ float smem[4][5];   // 4 waves per block
    const int wave = tid >> 6;
    const int lane = tid & 63;
    if (lane == 0) {
        smem[wave][0] = sx;  smem[wave][1] = sy;  smem[wave][2] = sxy;
        smem[wave][3] = sxx; smem[wave][4] = syy;
    }
    __syncthreads();

    if (tid == 0) {
        float tx = 0.f, ty = 0.f, txy = 0.f, txx = 0.f, tyy = 0.f;
        #pragma unroll
        for (int w = 0; w < BLOCK / 64; ++w) {
            tx  += smem[w][0]; ty  += smem[w][1]; txy += smem[w][2];
            txx += smem[w][3]; tyy += smem[w][4];
        }
        const float Nf  = (float)N_COLS;
        const float num = Nf * txy - tx * ty;
        const float den = sqrtf((Nf * txx - tx * tx) * (Nf * tyy - ty * ty));
        row_loss[row] = 1.0f - num / den;
    }
}

// Reduce 4096 per-row losses to the mean. Single block.
__global__ __launch_bounds__(BLOCK) void mean_kernel(
    const float* __restrict__ row_loss,
    float* __restrict__ out)
{
    const int tid = threadIdx.x;

    float s = 0.f;
    #pragma unroll
    for (int i = 0; i < B_ROWS / BLOCK; ++i)
        s += row_loss[tid + i * BLOCK];

    #pragma unroll
    for (int off = 32; off > 0; off >>= 1)
        s += __shfl_down(s, off);

    __shared__ float smem[4];
    const int wave = tid >> 6;
    const int lane = tid & 63;
    if (lane == 0) smem[wave] = s;
    __syncthreads();

    if (tid == 0) {
        float t = smem[0] + smem[1] + smem[2] + smem[3];
        out[0] = t / (float)B_ROWS;
    }
}

extern "C" void kernel_launch(void* const* d_in, const int* in_sizes, int n_in,
                              void* d_out, int out_size, void* d_ws, size_t ws_size,
                              hipStream_t stream) {
    const float* preds  = (const float*)d_in[0];
    const float* labels = (const float*)d_in[1];
    float* row_loss = (float*)d_ws;      // 4096 floats of scratch
    float* out      = (float*)d_out;

    row_pearson_kernel<<<B_ROWS, BLOCK, 0, stream>>>(preds, labels, row_loss);
    mean_kernel<<<1, BLOCK, 0, stream>>>(row_loss, out);
}